// Round 2
// baseline (336.610 us; speedup 1.0000x reference)
//
#include <hip/hip_runtime.h>
#include <cstdint>

// Problem constants (fixed by reference): B=16384 rows, C=4096 classes.
#define CLS   4096
#define NROWS 16384
#define RPB   8                  // rows owned per block
#define NBLK  (NROWS / RPB)      // 2048 blocks
#define NACC  64                 // spread accumulator slots (contention /64)

static __device__ __forceinline__ float wave_reduce_max(float v) {
    #pragma unroll
    for (int off = 32; off > 0; off >>= 1)
        v = fmaxf(v, __shfl_down(v, off, 64));
    return v;
}
static __device__ __forceinline__ float wave_reduce_sum(float v) {
    #pragma unroll
    for (int off = 32; off > 0; off >>= 1)
        v += __shfl_down(v, off, 64);
    return v;
}

// ws is re-poisoned to 0xAA before every timed launch: zero the accumulators.
__global__ void init_acc(float* __restrict__ acc) {
    if (threadIdx.x < NACC) acc[threadIdx.x] = 0.f;
}

// One block owns RPB consecutive rows. Phase 1: scan ALL indices (64 KB,
// L2-resident) and resolve last-write-wins winners for our rows in LDS:
// key = (i+1)<<32 | idx, 64-bit atomicMax -> max i wins (numpy fancy-assign
// semantics), payload idx recovers v[idx]. Phase 2: masked cross-entropy for
// rows with nonzero temp_v (~32% of rows), row cached in registers.
__global__ __launch_bounds__(256)
void spl_fused(const float* __restrict__ input,
               const float* __restrict__ v,
               const int* __restrict__ target,
               const int* __restrict__ index,
               float* __restrict__ acc) {
    const int t = threadIdx.x;
    const int rowBase = blockIdx.x * RPB;

    __shared__ unsigned long long win[RPB];
    __shared__ float vval[RPB];
    __shared__ float red_m[4], red_s[4];

    if (t < RPB) win[t] = 0ull;
    __syncthreads();

    // ---- Phase 1: index scan (int4-vectorized, 16 loads/thread) ----
    const int4* idx4 = (const int4*)index;
    #pragma unroll
    for (int j = 0; j < 16; ++j) {
        int4 q = idx4[t + 256 * j];
        int ib = 4 * (t + 256 * j);
        int e[4] = {q.x, q.y, q.z, q.w};
        #pragma unroll
        for (int k = 0; k < 4; ++k) {
            int pos = e[k] & (NROWS - 1);          // idx % B (B = 2^14)
            if ((pos >> 3) == (int)blockIdx.x) {   // pos / RPB == our block
                unsigned long long key =
                    ((unsigned long long)(unsigned)(ib + k + 1) << 32) |
                    (unsigned long long)(unsigned)e[k];
                atomicMax(&win[pos & (RPB - 1)], key);
            }
        }
    }
    __syncthreads();

    // Prefetch the (rare) v-gathers for our rows in parallel.
    if (t < RPB) {
        unsigned long long w = win[t];
        vval[t] = (w == 0ull) ? 0.f : v[(unsigned)(w & 0xFFFFFFFFull)];
    }
    __syncthreads();

    // ---- Phase 2: masked cross-entropy over our rows ----
    float blocksum = 0.f;
    for (int r = 0; r < RPB; ++r) {
        float val = vval[r];              // block-uniform
        if (val == 0.f) continue;         // never-written or v==0: contributes 0
        const int row = rowBase + r;
        const float4* rp = (const float4*)(input + (size_t)row * CLS);
        float4 x[4];
        #pragma unroll
        for (int j = 0; j < 4; ++j) x[j] = rp[t + 256 * j];
        float xt = 0.f;
        if (t == 0) xt = input[(size_t)row * CLS + target[row]];

        float m = -INFINITY;
        #pragma unroll
        for (int j = 0; j < 4; ++j)
            m = fmaxf(m, fmaxf(fmaxf(x[j].x, x[j].y), fmaxf(x[j].z, x[j].w)));
        m = wave_reduce_max(m);
        if ((t & 63) == 0) red_m[t >> 6] = m;
        __syncthreads();
        float bm = fmaxf(fmaxf(red_m[0], red_m[1]), fmaxf(red_m[2], red_m[3]));

        float s = 0.f;
        #pragma unroll
        for (int j = 0; j < 4; ++j)
            s += __expf(x[j].x - bm) + __expf(x[j].y - bm) +
                 __expf(x[j].z - bm) + __expf(x[j].w - bm);
        s = wave_reduce_sum(s);
        if ((t & 63) == 0) red_s[t >> 6] = s;
        __syncthreads();

        if (t == 0) {
            float tot = red_s[0] + red_s[1] + red_s[2] + red_s[3];
            blocksum += (bm + __logf(tot) - xt) * val;   // -logp[target] * mask
        }
    }
    if (t == 0 && blocksum != 0.f)
        atomicAdd(&acc[blockIdx.x & (NACC - 1)], blocksum);
}

__global__ void finalize(const float* __restrict__ acc, float* __restrict__ out) {
    int t = threadIdx.x;                 // 64 threads
    float s = (t < NACC) ? acc[t] : 0.f;
    s = wave_reduce_sum(s);
    if (t == 0) out[0] = s / (float)NROWS;
}

extern "C" void kernel_launch(void* const* d_in, const int* in_sizes, int n_in,
                              void* d_out, int out_size, void* d_ws, size_t ws_size,
                              hipStream_t stream) {
    const float* input  = (const float*)d_in[0];   // [B, C] fp32
    const float* v      = (const float*)d_in[1];   // [N] fp32
    const int*   target = (const int*)d_in[2];     // [B] int32
    const int*   index  = (const int*)d_in[3];     // [B] int32
    float* out = (float*)d_out;

    float* acc = (float*)d_ws;                     // NACC floats

    init_acc<<<1, 64, 0, stream>>>(acc);
    spl_fused<<<NBLK, 256, 0, stream>>>(input, v, target, index, acc);
    finalize<<<1, 64, 0, stream>>>(acc, out);
}